// Round 1
// baseline (2995.480 us; speedup 1.0000x reference)
//
#include <hip/hip_runtime.h>
#include <math.h>

#define DD 128
#define EDD 64

// ---------------- fused q/k/v/skip linears: 4 rows per 128-thread block ----------------
__global__ __launch_bounds__(128) void lin4_kernel(
    const float* __restrict__ x,
    const float* __restrict__ Wq, const float* __restrict__ bq,
    const float* __restrict__ Wk, const float* __restrict__ bk,
    const float* __restrict__ Wv, const float* __restrict__ bv,
    const float* __restrict__ Ws, const float* __restrict__ bs,
    float* __restrict__ q, float* __restrict__ k, float* __restrict__ v,
    float* __restrict__ pre, int N)
{
    __shared__ float xs[4][DD];
    int tid = threadIdx.x;
    int r0 = blockIdx.x * 4;
    for (int r = 0; r < 4; r++) {
        int row = r0 + r;
        xs[r][tid] = (row < N) ? x[(size_t)row * DD + tid] : 0.f;
    }
    __syncthreads();
    float aq[4], ak[4], av[4], as_[4];
    float bqv = bq[tid], bkv = bk[tid], bvv = bv[tid], bsv = bs[tid];
    #pragma unroll
    for (int r = 0; r < 4; r++) { aq[r] = bqv; ak[r] = bkv; av[r] = bvv; as_[r] = bsv; }
    for (int kk = 0; kk < DD; kk++) {
        float wq = Wq[kk * DD + tid], wk = Wk[kk * DD + tid];
        float wv = Wv[kk * DD + tid], ws = Ws[kk * DD + tid];
        #pragma unroll
        for (int r = 0; r < 4; r++) {
            float xv = xs[r][kk];
            aq[r] += xv * wq; ak[r] += xv * wk; av[r] += xv * wv; as_[r] += xv * ws;
        }
    }
    for (int r = 0; r < 4; r++) {
        int row = r0 + r;
        if (row >= N) break;
        size_t o = (size_t)row * DD + tid;
        q[o] = aq[r]; k[o] = ak[r]; v[o] = av[r];
        pre[o] = xs[r][tid] + as_[r];   // x + (x@Ws + bs)
    }
}

// ---------------- histogram (edges by dst / sub rows by indicator) ----------------
__global__ void count_kernel(const int* __restrict__ idx, int n, int* __restrict__ cnt)
{
    int i = blockIdx.x * blockDim.x + threadIdx.x;
    int stride = gridDim.x * blockDim.x;
    for (; i < n; i += stride) atomicAdd(&cnt[idx[i]], 1);
}

// ---------------- single-block exclusive scan (N=50000, 49 chunks of 1024) ----------------
__global__ __launch_bounds__(1024) void scan_kernel(const int* __restrict__ deg, int N,
                                                    int* __restrict__ indptr, int* __restrict__ fill)
{
    __shared__ int s[1024];
    int tid = threadIdx.x;
    int running = 0;
    for (int base = 0; base < N; base += 1024) {
        int i = base + tid;
        int val = (i < N) ? deg[i] : 0;
        s[tid] = val; __syncthreads();
        for (int off = 1; off < 1024; off <<= 1) {
            int t = (tid >= off) ? s[tid - off] : 0;
            __syncthreads();
            s[tid] += t;
            __syncthreads();
        }
        int excl = s[tid] - val;
        if (i < N) { indptr[i] = running + excl; fill[i] = running + excl; }
        int tot = s[1023];
        __syncthreads();
        running += tot;
    }
    if (tid == 0) indptr[N] = running;
}

// ---------------- scatter edge ids into dst-CSR ----------------
__global__ void escatter_kernel(const int* __restrict__ srcA, const int* __restrict__ dstA, int E,
                                int* __restrict__ fill, int* __restrict__ ssrc, int* __restrict__ seid)
{
    int i = blockIdx.x * blockDim.x + threadIdx.x;
    int stride = gridDim.x * blockDim.x;
    for (; i < E; i += stride) {
        int d = dstA[i];
        int pos = atomicAdd(&fill[d], 1);
        ssrc[pos] = srcA[i];
        seid[pos] = i;
    }
}

// ---------------- attention: 1 wave per dst node, online softmax, e computed on the fly ----------------
__global__ __launch_bounds__(256) void attn_kernel(
    const float* __restrict__ q, const float* __restrict__ k, const float* __restrict__ v,
    const float* __restrict__ edge_attr, const float* __restrict__ We, const float* __restrict__ be,
    const int* __restrict__ indptr, const int* __restrict__ ssrc, const int* __restrict__ seid,
    float* __restrict__ pre, int N)
{
    __shared__ float WeS[EDD * DD];   // 32 KB
    __shared__ float beS[DD];
    int tid = threadIdx.x;
    for (int idx = tid; idx < EDD * DD; idx += 256) WeS[idx] = We[idx];
    if (tid < DD) beS[tid] = be[tid];
    __syncthreads();

    int wave = tid >> 6, lane = tid & 63;
    int n = blockIdx.x * 4 + wave;
    if (n >= N) return;
    int c0 = lane * 2;
    float qv0 = q[(size_t)n * DD + c0], qv1 = q[(size_t)n * DD + c0 + 1];
    float be0 = beS[c0], be1 = beS[c0 + 1];
    int start = indptr[n], end = indptr[n + 1];
    float m = -INFINITY, s = 0.f, a0 = 0.f, a1 = 0.f;
    const float2* WeS2 = (const float2*)WeS;

    for (int ii = start; ii < end; ii++) {
        int src = ssrc[ii];
        int eid = seid[ii];
        float ear = edge_attr[(size_t)eid * EDD + lane];  // lane j holds edge_attr[eid][j]
        float e0 = be0, e1 = be1;
        #pragma unroll 8
        for (int j = 0; j < EDD; j++) {
            float a = __shfl(ear, j);
            float2 w = WeS2[j * 64 + lane];
            e0 += a * w.x; e1 += a * w.y;
        }
        float ke0 = k[(size_t)src * DD + c0]     + e0;
        float ke1 = k[(size_t)src * DD + c0 + 1] + e1;
        float part = qv0 * ke0 + qv1 * ke1;
        part += __shfl_xor(part, 1);
        part += __shfl_xor(part, 2);
        part += __shfl_xor(part, 4);      // sum over the 8 lanes of this head (C=16, 2 ch/lane)
        float alpha = part * 0.25f;       // / sqrt(16)
        float nm = fmaxf(m, alpha);
        float sc = expf(m - nm);          // first edge: exp(-inf) = 0
        float p  = expf(alpha - nm);
        s = s * sc + p;
        float v0 = v[(size_t)src * DD + c0]     + e0;
        float v1 = v[(size_t)src * DD + c0 + 1] + e1;
        a0 = a0 * sc + p * v0;
        a1 = a1 * sc + p * v1;
        m = nm;
    }
    if (end > start) {
        float inv = 1.f / s;
        pre[(size_t)n * DD + c0]     += a0 * inv;
        pre[(size_t)n * DD + c0 + 1] += a1 * inv;
    }
}

// ---------------- subgraph branch: gather -> LN -> MLP(SiLU) -> atomic scatter-add ----------------
__global__ __launch_bounds__(128) void submlp_kernel(
    const float* __restrict__ x, const int* __restrict__ sub_nodes, const int* __restrict__ sub_ind,
    const float* __restrict__ sn_g, const float* __restrict__ sn_b,
    const float* __restrict__ p1w, const float* __restrict__ p1b,
    const float* __restrict__ p2w, const float* __restrict__ p2b,
    float* __restrict__ accum, int M)
{
    __shared__ float xs[8][DD];
    __shared__ float hs[8][DD];
    __shared__ float red[4];
    __shared__ int segS[8];
    int tid = threadIdx.x;
    size_t m0 = (size_t)blockIdx.x * 8;
    if (tid < 8) {
        size_t row = m0 + tid;
        segS[tid] = (row < (size_t)M) ? sub_ind[row] : -1;
    }
    for (int r = 0; r < 8; r++) {
        size_t row = m0 + r;
        if (row < (size_t)M) {
            int node = sub_nodes[row];
            xs[r][tid] = x[(size_t)node * DD + tid];
        } else xs[r][tid] = 0.f;
    }
    __syncthreads();
    float gv = sn_g[tid], bvv = sn_b[tid];
    for (int r = 0; r < 8; r++) {
        float val = xs[r][tid];
        float s1 = val, s2 = val * val;
        for (int o = 32; o >= 1; o >>= 1) { s1 += __shfl_xor(s1, o); s2 += __shfl_xor(s2, o); }
        int w = tid >> 6;
        if ((tid & 63) == 0) { red[2 * w] = s1; red[2 * w + 1] = s2; }
        __syncthreads();
        float mean = (red[0] + red[2]) * (1.f / DD);
        float var  = (red[1] + red[3]) * (1.f / DD) - mean * mean;
        float nsv = (val - mean) * rsqrtf(var + 1e-5f) * gv + bvv;
        __syncthreads();
        xs[r][tid] = nsv;
    }
    __syncthreads();
    float acc[8];
    float b1 = p1b[tid];
    #pragma unroll
    for (int r = 0; r < 8; r++) acc[r] = b1;
    for (int kk = 0; kk < DD; kk++) {
        float wv = p1w[kk * DD + tid];
        #pragma unroll
        for (int r = 0; r < 8; r++) acc[r] += xs[r][kk] * wv;
    }
    for (int r = 0; r < 8; r++) {
        float a = acc[r];
        hs[r][tid] = a / (1.f + expf(-a));   // SiLU
    }
    __syncthreads();
    float b2 = p2b[tid];
    #pragma unroll
    for (int r = 0; r < 8; r++) acc[r] = b2;
    for (int kk = 0; kk < DD; kk++) {
        float wv = p2w[kk * DD + tid];
        #pragma unroll
        for (int r = 0; r < 8; r++) acc[r] += hs[r][kk] * wv;
    }
    for (int r = 0; r < 8; r++) {
        int seg = segS[r];
        if (seg >= 0) atomicAdd(&accum[(size_t)seg * DD + tid], acc[r]);
    }
}

// ---------------- final combine: LN + SiLU ----------------
__global__ __launch_bounds__(128) void final_kernel(
    const float* __restrict__ pre, const float* __restrict__ accum, const int* __restrict__ cnt,
    const float* __restrict__ on_g, const float* __restrict__ on_b,
    float* __restrict__ out, int N)
{
    __shared__ float red[4];
    int tid = threadIdx.x;
    int n = blockIdx.x;
    float inv = 1.f / fmaxf((float)cnt[n], 1.f);
    size_t o = (size_t)n * DD + tid;
    float val = pre[o] + accum[o] * inv;
    float s1 = val, s2 = val * val;
    for (int off = 32; off >= 1; off >>= 1) { s1 += __shfl_xor(s1, off); s2 += __shfl_xor(s2, off); }
    int w = tid >> 6;
    if ((tid & 63) == 0) { red[2 * w] = s1; red[2 * w + 1] = s2; }
    __syncthreads();
    float mean = (red[0] + red[2]) * (1.f / DD);
    float var  = (red[1] + red[3]) * (1.f / DD) - mean * mean;
    float ov = (val - mean) * rsqrtf(var + 1e-5f) * on_g[tid] + on_b[tid];
    out[o] = ov / (1.f + expf(-ov));
}

extern "C" void kernel_launch(void* const* d_in, const int* in_sizes, int n_in,
                              void* d_out, int out_size, void* d_ws, size_t ws_size,
                              hipStream_t stream)
{
    const float* x         = (const float*)d_in[0];
    const int*   edge_index= (const int*)  d_in[1];
    const float* edge_attr = (const float*)d_in[2];
    const int*   sub_nodes = (const int*)  d_in[3];
    const int*   sub_ind   = (const int*)  d_in[4];
    const float* Wq = (const float*)d_in[5];  const float* bq = (const float*)d_in[6];
    const float* Wk = (const float*)d_in[7];  const float* bk = (const float*)d_in[8];
    const float* Wv = (const float*)d_in[9];  const float* bv = (const float*)d_in[10];
    const float* We = (const float*)d_in[11]; const float* be = (const float*)d_in[12];
    const float* Ws = (const float*)d_in[13]; const float* bs = (const float*)d_in[14];
    const float* sn_g = (const float*)d_in[15]; const float* sn_b = (const float*)d_in[16];
    const float* p1w = (const float*)d_in[17]; const float* p1b = (const float*)d_in[18];
    const float* p2w = (const float*)d_in[19]; const float* p2b = (const float*)d_in[20];
    const float* on_g = (const float*)d_in[21]; const float* on_b = (const float*)d_in[22];

    int N = in_sizes[0] / DD;
    int E = in_sizes[1] / 2;
    int M = in_sizes[3];
    float* out = (float*)d_out;

    // workspace layout (~135 MB): 5 N*D float arrays + CSR ints
    size_t ND = (size_t)N * DD;
    float* q     = (float*)d_ws;
    float* k     = q + ND;
    float* v     = k + ND;
    float* pre   = v + ND;
    float* accum = pre + ND;
    int* indptr = (int*)(accum + ND);   // N+1
    int* fill   = indptr + (N + 1);     // N
    int* deg    = fill + N;             // N
    int* cnt    = deg + N;              // N
    int* ssrc   = cnt + N;              // E
    int* seid   = ssrc + E;             // E

    const int* srcA = edge_index;
    const int* dstA = edge_index + E;

    hipMemsetAsync(deg, 0, (size_t)N * sizeof(int), stream);
    hipMemsetAsync(cnt, 0, (size_t)N * sizeof(int), stream);
    hipMemsetAsync(accum, 0, ND * sizeof(float), stream);

    lin4_kernel<<<(N + 3) / 4, 128, 0, stream>>>(x, Wq, bq, Wk, bk, Wv, bv, Ws, bs, q, k, v, pre, N);
    count_kernel<<<2048, 256, 0, stream>>>(dstA, E, deg);
    count_kernel<<<2048, 256, 0, stream>>>(sub_ind, M, cnt);
    scan_kernel<<<1, 1024, 0, stream>>>(deg, N, indptr, fill);
    escatter_kernel<<<2048, 256, 0, stream>>>(srcA, dstA, E, fill, ssrc, seid);
    attn_kernel<<<(N + 3) / 4, 256, 0, stream>>>(q, k, v, edge_attr, We, be, indptr, ssrc, seid, pre, N);
    submlp_kernel<<<(M + 7) / 8, 128, 0, stream>>>(x, sub_nodes, sub_ind, sn_g, sn_b, p1w, p1b, p2w, p2b, accum, M);
    final_kernel<<<N, 128, 0, stream>>>(pre, accum, cnt, on_g, on_b, out, N);
}

// Round 2
// 1846.331 us; speedup vs baseline: 1.6224x; 1.6224x over previous
//
#include <hip/hip_runtime.h>
#include <math.h>

#define DD 128
#define EDD 64

typedef __attribute__((ext_vector_type(8))) short bf16x8;
typedef __attribute__((ext_vector_type(4))) float f32x4;

__device__ inline unsigned short f2bf(float f) {
    unsigned int u = __float_as_uint(f);
    u += 0x7FFFu + ((u >> 16) & 1u);
    return (unsigned short)(u >> 16);
}
__device__ inline unsigned int pack2bf16(float lo, float hi) {
    return (unsigned int)f2bf(lo) | ((unsigned int)f2bf(hi) << 16);
}

// ---------------- fused q/k/v/skip linears: 4 rows per 128-thread block ----------------
__global__ __launch_bounds__(128) void lin4_kernel(
    const float* __restrict__ x,
    const float* __restrict__ Wq, const float* __restrict__ bq,
    const float* __restrict__ Wk, const float* __restrict__ bk,
    const float* __restrict__ Wv, const float* __restrict__ bv,
    const float* __restrict__ Ws, const float* __restrict__ bs,
    float* __restrict__ q, float* __restrict__ k, float* __restrict__ v,
    float* __restrict__ pre, int N)
{
    __shared__ float xs[4][DD];
    int tid = threadIdx.x;
    int r0 = blockIdx.x * 4;
    for (int r = 0; r < 4; r++) {
        int row = r0 + r;
        xs[r][tid] = (row < N) ? x[(size_t)row * DD + tid] : 0.f;
    }
    __syncthreads();
    float aq[4], ak[4], av[4], as_[4];
    float bqv = bq[tid], bkv = bk[tid], bvv = bv[tid], bsv = bs[tid];
    #pragma unroll
    for (int r = 0; r < 4; r++) { aq[r] = bqv; ak[r] = bkv; av[r] = bvv; as_[r] = bsv; }
    for (int kk = 0; kk < DD; kk++) {
        float wq = Wq[kk * DD + tid], wk = Wk[kk * DD + tid];
        float wv = Wv[kk * DD + tid], ws = Ws[kk * DD + tid];
        #pragma unroll
        for (int r = 0; r < 4; r++) {
            float xv = xs[r][kk];
            aq[r] += xv * wq; ak[r] += xv * wk; av[r] += xv * wv; as_[r] += xv * ws;
        }
    }
    for (int r = 0; r < 4; r++) {
        int row = r0 + r;
        if (row >= N) break;
        size_t o = (size_t)row * DD + tid;
        q[o] = aq[r]; k[o] = ak[r]; v[o] = av[r];
        pre[o] = xs[r][tid] + as_[r];   // x + (x@Ws + bs)
    }
}

// ---------------- histogram ----------------
__global__ void count_kernel(const int* __restrict__ idx, int n, int* __restrict__ cnt)
{
    int i = blockIdx.x * blockDim.x + threadIdx.x;
    int stride = gridDim.x * blockDim.x;
    for (; i < n; i += stride) atomicAdd(&cnt[idx[i]], 1);
}

// ---------------- single-block exclusive scan ----------------
__global__ __launch_bounds__(1024) void scan_kernel(const int* __restrict__ deg, int N,
                                                    int* __restrict__ indptr, int* __restrict__ fill)
{
    __shared__ int s[1024];
    int tid = threadIdx.x;
    int running = 0;
    for (int base = 0; base < N; base += 1024) {
        int i = base + tid;
        int val = (i < N) ? deg[i] : 0;
        s[tid] = val; __syncthreads();
        for (int off = 1; off < 1024; off <<= 1) {
            int t = (tid >= off) ? s[tid - off] : 0;
            __syncthreads();
            s[tid] += t;
            __syncthreads();
        }
        int excl = s[tid] - val;
        if (i < N) { indptr[i] = running + excl; fill[i] = running + excl; }
        int tot = s[1023];
        __syncthreads();
        running += tot;
    }
    if (tid == 0) indptr[N] = running;
}

// ---------------- scatter edge ids into dst-CSR ----------------
__global__ void escatter_kernel(const int* __restrict__ srcA, const int* __restrict__ dstA, int E,
                                int* __restrict__ fill, int* __restrict__ ssrc, int* __restrict__ seid)
{
    int i = blockIdx.x * blockDim.x + threadIdx.x;
    int stride = gridDim.x * blockDim.x;
    for (; i < E; i += stride) {
        int d = dstA[i];
        int pos = atomicAdd(&fill[d], 1);
        ssrc[pos] = srcA[i];
        seid[pos] = i;
    }
}

// ---------------- attention: 1 wave per dst node, online softmax ----------------
__global__ __launch_bounds__(256) void attn_kernel(
    const float* __restrict__ q, const float* __restrict__ k, const float* __restrict__ v,
    const float* __restrict__ edge_attr, const float* __restrict__ We, const float* __restrict__ be,
    const int* __restrict__ indptr, const int* __restrict__ ssrc, const int* __restrict__ seid,
    float* __restrict__ pre, int N)
{
    __shared__ float WeS[EDD * DD];   // 32 KB
    __shared__ float beS[DD];
    int tid = threadIdx.x;
    for (int idx = tid; idx < EDD * DD; idx += 256) WeS[idx] = We[idx];
    if (tid < DD) beS[tid] = be[tid];
    __syncthreads();

    int wave = tid >> 6, lane = tid & 63;
    int n = blockIdx.x * 4 + wave;
    if (n >= N) return;
    int c0 = lane * 2;
    float qv0 = q[(size_t)n * DD + c0], qv1 = q[(size_t)n * DD + c0 + 1];
    float be0 = beS[c0], be1 = beS[c0 + 1];
    int start = indptr[n], end = indptr[n + 1];
    float m = -INFINITY, s = 0.f, a0 = 0.f, a1 = 0.f;
    const float2* WeS2 = (const float2*)WeS;

    for (int ii = start; ii < end; ii++) {
        int src = ssrc[ii];
        int eid = seid[ii];
        float ear = edge_attr[(size_t)eid * EDD + lane];
        float e0 = be0, e1 = be1;
        #pragma unroll 8
        for (int j = 0; j < EDD; j++) {
            float a = __shfl(ear, j);
            float2 w = WeS2[j * 64 + lane];
            e0 += a * w.x; e1 += a * w.y;
        }
        float ke0 = k[(size_t)src * DD + c0]     + e0;
        float ke1 = k[(size_t)src * DD + c0 + 1] + e1;
        float part = qv0 * ke0 + qv1 * ke1;
        part += __shfl_xor(part, 1);
        part += __shfl_xor(part, 2);
        part += __shfl_xor(part, 4);
        float alpha = part * 0.25f;
        float nm = fmaxf(m, alpha);
        float sc = expf(m - nm);
        float p  = expf(alpha - nm);
        s = s * sc + p;
        float v0 = v[(size_t)src * DD + c0]     + e0;
        float v1 = v[(size_t)src * DD + c0 + 1] + e1;
        a0 = a0 * sc + p * v0;
        a1 = a1 * sc + p * v1;
        m = nm;
    }
    if (end > start) {
        float inv = 1.f / s;
        pre[(size_t)n * DD + c0]     += a0 * inv;
        pre[(size_t)n * DD + c0 + 1] += a1 * inv;
    }
}

// ---------------- pack a [128][128] fp32 weight into bf16 MFMA B-fragment order ----------------
// packed[((ncf*4+kt)*64 + lane)*8 + j] = bf16( w[(kt*32 + (lane>>4)*8 + j)*128 + ncf*16 + (lane&15)] )
__global__ __launch_bounds__(256) void packw_kernel(const float* __restrict__ w,
                                                    unsigned short* __restrict__ packed)
{
    int idx = blockIdx.x * 256 + threadIdx.x;
    if (idx >= DD * DD) return;
    int j    = idx & 7;
    int lane = (idx >> 3) & 63;
    int kt   = (idx >> 9) & 3;
    int ncf  = idx >> 11;
    int kk  = kt * 32 + (lane >> 4) * 8 + j;
    int col = ncf * 16 + (lane & 15);
    packed[idx] = f2bf(w[kk * DD + col]);
}

// ---------------- subgraph branch via MFMA: gather -> LN -> bf16 GEMM -> SiLU -> bf16 GEMM -> atomics
// 64 rows / block, 256 threads (2x2 wave grid, each wave = 32 rows x 64 cols).
__global__ __launch_bounds__(256, 4) void submlp_mfma_kernel(
    const float* __restrict__ x, const int* __restrict__ sub_nodes, const int* __restrict__ sub_ind,
    const float* __restrict__ sn_g, const float* __restrict__ sn_b,
    const unsigned short* __restrict__ packB1, const float* __restrict__ p1b,
    const unsigned short* __restrict__ packB2, const float* __restrict__ p2b,
    float* __restrict__ accum, int M)
{
    __shared__ unsigned short sxs[64 * DD];   // 16 KB, XOR-swizzled bf16
    __shared__ unsigned short hss[64 * DD];   // 16 KB
    __shared__ int segS[64];
    int tid = threadIdx.x;
    int lane = tid & 63, wid = tid >> 6;
    size_t m0 = (size_t)blockIdx.x * 64;

    if (tid < 64) {
        size_t row = m0 + tid;
        segS[tid] = (row < (size_t)M) ? sub_ind[row] : -1;
    }

    // ---- LN phase: wave wid owns tile rows [wid*16, wid*16+16) ----
    {
        float g0 = sn_g[2 * lane], g1 = sn_g[2 * lane + 1];
        float b0 = sn_b[2 * lane], b1 = sn_b[2 * lane + 1];
        #pragma unroll
        for (int r = 0; r < 16; r++) {
            int tr = wid * 16 + r;
            size_t row = m0 + tr;
            float v0 = 0.f, v1 = 0.f;
            if (row < (size_t)M) {
                int node = sub_nodes[row];
                float2 xv = *(const float2*)&x[(size_t)node * DD + 2 * lane];
                v0 = xv.x; v1 = xv.y;
            }
            float s1 = v0 + v1, s2 = v0 * v0 + v1 * v1;
            #pragma unroll
            for (int o = 32; o >= 1; o >>= 1) { s1 += __shfl_xor(s1, o); s2 += __shfl_xor(s2, o); }
            float mean = s1 * (1.f / DD);
            float var  = s2 * (1.f / DD) - mean * mean;
            float rs = rsqrtf(var + 1e-5f);
            float n0 = (v0 - mean) * rs * g0 + b0;
            float n1 = (v1 - mean) * rs * g1 + b1;
            // swizzled write: uint index (tr*64+lane) ^ ((tr&7)<<2)
            unsigned int uidx = ((unsigned)(tr * 64 + lane)) ^ (((unsigned)tr & 7u) << 2);
            ((unsigned int*)sxs)[uidx] = pack2bf16(n0, n1);
        }
    }
    __syncthreads();

    int wr = wid >> 1, wc = wid & 1;      // 2x2 wave grid
    int rA = wr * 32 + (lane & 15);       // A-frag row (add mrf*16)
    int kb = (lane >> 4) * 8;

    // ---- GEMM1: hs = silu(sx @ p1w + p1b) ----
    f32x4 acc[2][4];
    #pragma unroll
    for (int i = 0; i < 2; i++)
        #pragma unroll
        for (int j = 0; j < 4; j++) acc[i][j] = (f32x4){0.f, 0.f, 0.f, 0.f};

    #pragma unroll
    for (int kt = 0; kt < 4; kt++) {
        int k0 = kt * 32 + kb;
        bf16x8 a0 = *(const bf16x8*)&sxs[((rA)      * DD + k0) ^ ((rA & 7) << 3)];
        int rA1 = rA + 16;
        bf16x8 a1 = *(const bf16x8*)&sxs[((rA1)     * DD + k0) ^ ((rA1 & 7) << 3)];
        #pragma unroll
        for (int nc = 0; nc < 4; nc++) {
            bf16x8 b = *(const bf16x8*)&packB1[(((wc * 4 + nc) * 4 + kt) * 64 + lane) * 8];
            acc[0][nc] = __builtin_amdgcn_mfma_f32_16x16x32_bf16(a0, b, acc[0][nc], 0, 0, 0);
            acc[1][nc] = __builtin_amdgcn_mfma_f32_16x16x32_bf16(a1, b, acc[1][nc], 0, 0, 0);
        }
    }

    // epilogue1: bias + SiLU -> bf16 -> swizzled LDS
    {
        float bias1[4];
        #pragma unroll
        for (int nc = 0; nc < 4; nc++) bias1[nc] = p1b[wc * 64 + nc * 16 + (lane & 15)];
        #pragma unroll
        for (int mrf = 0; mrf < 2; mrf++) {
            int rbase = wr * 32 + mrf * 16 + (lane >> 4) * 4;
            #pragma unroll
            for (int nc = 0; nc < 4; nc++) {
                int col = wc * 64 + nc * 16 + (lane & 15);
                #pragma unroll
                for (int j = 0; j < 4; j++) {
                    float h = acc[mrf][nc][j] + bias1[nc];
                    h = h / (1.f + expf(-h));
                    int rr = rbase + j;
                    hss[(rr * DD + col) ^ ((rr & 7) << 3)] = f2bf(h);
                }
            }
        }
    }
    __syncthreads();

    // ---- GEMM2: out = hs @ p2w + p2b ----
    f32x4 acc2[2][4];
    #pragma unroll
    for (int i = 0; i < 2; i++)
        #pragma unroll
        for (int j = 0; j < 4; j++) acc2[i][j] = (f32x4){0.f, 0.f, 0.f, 0.f};

    #pragma unroll
    for (int kt = 0; kt < 4; kt++) {
        int k0 = kt * 32 + kb;
        bf16x8 a0 = *(const bf16x8*)&hss[((rA)      * DD + k0) ^ ((rA & 7) << 3)];
        int rA1 = rA + 16;
        bf16x8 a1 = *(const bf16x8*)&hss[((rA1)     * DD + k0) ^ ((rA1 & 7) << 3)];
        #pragma unroll
        for (int nc = 0; nc < 4; nc++) {
            bf16x8 b = *(const bf16x8*)&packB2[(((wc * 4 + nc) * 4 + kt) * 64 + lane) * 8];
            acc2[0][nc] = __builtin_amdgcn_mfma_f32_16x16x32_bf16(a0, b, acc2[0][nc], 0, 0, 0);
            acc2[1][nc] = __builtin_amdgcn_mfma_f32_16x16x32_bf16(a1, b, acc2[1][nc], 0, 0, 0);
        }
    }

    // epilogue2: bias + atomic scatter-add
    {
        float bias2[4];
        #pragma unroll
        for (int nc = 0; nc < 4; nc++) bias2[nc] = p2b[wc * 64 + nc * 16 + (lane & 15)];
        #pragma unroll
        for (int mrf = 0; mrf < 2; mrf++) {
            int rbase = wr * 32 + mrf * 16 + (lane >> 4) * 4;
            #pragma unroll
            for (int j = 0; j < 4; j++) {
                int rr = rbase + j;
                int seg = segS[rr];
                if (seg >= 0) {
                    #pragma unroll
                    for (int nc = 0; nc < 4; nc++) {
                        int col = wc * 64 + nc * 16 + (lane & 15);
                        atomicAdd(&accum[(size_t)seg * DD + col], acc2[mrf][nc][j] + bias2[nc]);
                    }
                }
            }
        }
    }
}

// ---------------- final combine: LN + SiLU ----------------
__global__ __launch_bounds__(128) void final_kernel(
    const float* __restrict__ pre, const float* __restrict__ accum, const int* __restrict__ cnt,
    const float* __restrict__ on_g, const float* __restrict__ on_b,
    float* __restrict__ out, int N)
{
    __shared__ float red[4];
    int tid = threadIdx.x;
    int n = blockIdx.x;
    float inv = 1.f / fmaxf((float)cnt[n], 1.f);
    size_t o = (size_t)n * DD + tid;
    float val = pre[o] + accum[o] * inv;
    float s1 = val, s2 = val * val;
    for (int off = 32; off >= 1; off >>= 1) { s1 += __shfl_xor(s1, off); s2 += __shfl_xor(s2, off); }
    int w = tid >> 6;
    if ((tid & 63) == 0) { red[2 * w] = s1; red[2 * w + 1] = s2; }
    __syncthreads();
    float mean = (red[0] + red[2]) * (1.f / DD);
    float var  = (red[1] + red[3]) * (1.f / DD) - mean * mean;
    float ov = (val - mean) * rsqrtf(var + 1e-5f) * on_g[tid] + on_b[tid];
    out[o] = ov / (1.f + expf(-ov));
}

extern "C" void kernel_launch(void* const* d_in, const int* in_sizes, int n_in,
                              void* d_out, int out_size, void* d_ws, size_t ws_size,
                              hipStream_t stream)
{
    const float* x         = (const float*)d_in[0];
    const int*   edge_index= (const int*)  d_in[1];
    const float* edge_attr = (const float*)d_in[2];
    const int*   sub_nodes = (const int*)  d_in[3];
    const int*   sub_ind   = (const int*)  d_in[4];
    const float* Wq = (const float*)d_in[5];  const float* bq = (const float*)d_in[6];
    const float* Wk = (const float*)d_in[7];  const float* bk = (const float*)d_in[8];
    const float* Wv = (const float*)d_in[9];  const float* bv = (const float*)d_in[10];
    const float* We = (const float*)d_in[11]; const float* be = (const float*)d_in[12];
    const float* Ws = (const float*)d_in[13]; const float* bs = (const float*)d_in[14];
    const float* sn_g = (const float*)d_in[15]; const float* sn_b = (const float*)d_in[16];
    const float* p1w = (const float*)d_in[17]; const float* p1b = (const float*)d_in[18];
    const float* p2w = (const float*)d_in[19]; const float* p2b = (const float*)d_in[20];
    const float* on_g = (const float*)d_in[21]; const float* on_b = (const float*)d_in[22];

    int N = in_sizes[0] / DD;
    int E = in_sizes[1] / 2;
    int M = in_sizes[3];
    float* out = (float*)d_out;

    // workspace layout: packed bf16 weights first (aligned), then 5 N*D float arrays + CSR ints
    unsigned short* packB1 = (unsigned short*)d_ws;   // 16384
    unsigned short* packB2 = packB1 + DD * DD;        // 16384
    size_t ND = (size_t)N * DD;
    float* q     = (float*)(packB2 + DD * DD);
    float* k     = q + ND;
    float* v     = k + ND;
    float* pre   = v + ND;
    float* accum = pre + ND;
    int* indptr = (int*)(accum + ND);   // N+1
    int* fill   = indptr + (N + 1);     // N
    int* deg    = fill + N;             // N
    int* cnt    = deg + N;              // N
    int* ssrc   = cnt + N;              // E
    int* seid   = ssrc + E;             // E

    const int* srcA = edge_index;
    const int* dstA = edge_index + E;

    hipMemsetAsync(deg, 0, (size_t)N * sizeof(int), stream);
    hipMemsetAsync(cnt, 0, (size_t)N * sizeof(int), stream);
    hipMemsetAsync(accum, 0, ND * sizeof(float), stream);

    packw_kernel<<<(DD * DD + 255) / 256, 256, 0, stream>>>(p1w, packB1);
    packw_kernel<<<(DD * DD + 255) / 256, 256, 0, stream>>>(p2w, packB2);

    lin4_kernel<<<(N + 3) / 4, 128, 0, stream>>>(x, Wq, bq, Wk, bk, Wv, bv, Ws, bs, q, k, v, pre, N);
    count_kernel<<<2048, 256, 0, stream>>>(dstA, E, deg);
    count_kernel<<<2048, 256, 0, stream>>>(sub_ind, M, cnt);
    scan_kernel<<<1, 1024, 0, stream>>>(deg, N, indptr, fill);
    escatter_kernel<<<2048, 256, 0, stream>>>(srcA, dstA, E, fill, ssrc, seid);
    attn_kernel<<<(N + 3) / 4, 256, 0, stream>>>(q, k, v, edge_attr, We, be, indptr, ssrc, seid, pre, N);
    submlp_mfma_kernel<<<(M + 63) / 64, 256, 0, stream>>>(x, sub_nodes, sub_ind, sn_g, sn_b,
                                                          packB1, p1b, packB2, p2b, accum, M);
    final_kernel<<<N, 128, 0, stream>>>(pre, accum, cnt, on_g, on_b, out, N);
}

// Round 3
// 1269.275 us; speedup vs baseline: 2.3600x; 1.4546x over previous
//
#include <hip/hip_runtime.h>
#include <math.h>

#define DD 128
#define EDD 64

typedef __attribute__((ext_vector_type(8))) short bf16x8;
typedef __attribute__((ext_vector_type(4))) float f32x4;

__device__ inline unsigned short f2bf(float f) {
    unsigned int u = __float_as_uint(f);
    u += 0x7FFFu + ((u >> 16) & 1u);
    return (unsigned short)(u >> 16);
}
__device__ inline unsigned int pack2bf16(float lo, float hi) {
    return (unsigned int)f2bf(lo) | ((unsigned int)f2bf(hi) << 16);
}

// ---------------- fused q/k/v/skip linears: 4 rows per 128-thread block ----------------
__global__ __launch_bounds__(128) void lin4_kernel(
    const float* __restrict__ x,
    const float* __restrict__ Wq, const float* __restrict__ bq,
    const float* __restrict__ Wk, const float* __restrict__ bk,
    const float* __restrict__ Wv, const float* __restrict__ bv,
    const float* __restrict__ Ws, const float* __restrict__ bs,
    float* __restrict__ q, float* __restrict__ k, float* __restrict__ v,
    float* __restrict__ pre, int N)
{
    __shared__ float xs[4][DD];
    int tid = threadIdx.x;
    int r0 = blockIdx.x * 4;
    for (int r = 0; r < 4; r++) {
        int row = r0 + r;
        xs[r][tid] = (row < N) ? x[(size_t)row * DD + tid] : 0.f;
    }
    __syncthreads();
    float aq[4], ak[4], av[4], as_[4];
    float bqv = bq[tid], bkv = bk[tid], bvv = bv[tid], bsv = bs[tid];
    #pragma unroll
    for (int r = 0; r < 4; r++) { aq[r] = bqv; ak[r] = bkv; av[r] = bvv; as_[r] = bsv; }
    for (int kk = 0; kk < DD; kk++) {
        float wq = Wq[kk * DD + tid], wk = Wk[kk * DD + tid];
        float wv = Wv[kk * DD + tid], ws = Ws[kk * DD + tid];
        #pragma unroll
        for (int r = 0; r < 4; r++) {
            float xv = xs[r][kk];
            aq[r] += xv * wq; ak[r] += xv * wk; av[r] += xv * wv; as_[r] += xv * ws;
        }
    }
    for (int r = 0; r < 4; r++) {
        int row = r0 + r;
        if (row >= N) break;
        size_t o = (size_t)row * DD + tid;
        q[o] = aq[r]; k[o] = ak[r]; v[o] = av[r];
        pre[o] = xs[r][tid] + as_[r];   // x + (x@Ws + bs)
    }
}

// ---------------- histogram ----------------
__global__ void count_kernel(const int* __restrict__ idx, int n, int* __restrict__ cnt)
{
    int i = blockIdx.x * blockDim.x + threadIdx.x;
    int stride = gridDim.x * blockDim.x;
    for (; i < n; i += stride) atomicAdd(&cnt[idx[i]], 1);
}

// ---------------- single-block exclusive scan ----------------
__global__ __launch_bounds__(1024) void scan_kernel(const int* __restrict__ deg, int N,
                                                    int* __restrict__ indptr, int* __restrict__ fill)
{
    __shared__ int s[1024];
    int tid = threadIdx.x;
    int running = 0;
    for (int base = 0; base < N; base += 1024) {
        int i = base + tid;
        int val = (i < N) ? deg[i] : 0;
        s[tid] = val; __syncthreads();
        for (int off = 1; off < 1024; off <<= 1) {
            int t = (tid >= off) ? s[tid - off] : 0;
            __syncthreads();
            s[tid] += t;
            __syncthreads();
        }
        int excl = s[tid] - val;
        if (i < N) { indptr[i] = running + excl; fill[i] = running + excl; }
        int tot = s[1023];
        __syncthreads();
        running += tot;
    }
    if (tid == 0) indptr[N] = running;
}

// ---------------- scatter edge ids into dst-CSR ----------------
__global__ void escatter_kernel(const int* __restrict__ srcA, const int* __restrict__ dstA, int E,
                                int* __restrict__ fill, int* __restrict__ ssrc, int* __restrict__ seid)
{
    int i = blockIdx.x * blockDim.x + threadIdx.x;
    int stride = gridDim.x * blockDim.x;
    for (; i < E; i += stride) {
        int d = dstA[i];
        int pos = atomicAdd(&fill[d], 1);
        ssrc[pos] = srcA[i];
        seid[pos] = i;
    }
}

// ---------------- attention v3: 1 wave per dst node, algebraic e-refactor ----------------
// alpha[h] = (q.k[src] + sum_j ea[j]*qWe[j][h] + q.be) / 4, qWe precomputed per node.
// Value-side e deferred: accumulate aea[h][j] = sum p*ea[j]; apply We once per node.
// Lane L = 8*g + jj (g = head, jj = 0..7); channels c0 = 2L, c0+1 (head g owns lanes 8g..8g+7).
// qWe[r] in lane L = qWe[jj+8r][g]; aea[r] likewise.
__global__ __launch_bounds__(512, 6) void attn_kernel(
    const float* __restrict__ q, const float* __restrict__ k, const float* __restrict__ v,
    const float* __restrict__ edge_attr, const float* __restrict__ We, const float* __restrict__ be,
    const int* __restrict__ indptr, const int* __restrict__ ssrc, const int* __restrict__ seid,
    float* __restrict__ pre, int N)
{
    __shared__ float WeT[DD * 65];   // WeT[c*65 + j] = We[j*128 + c], pad 65 -> 4-way max conflict
    int tid = threadIdx.x;
    for (int idx = tid; idx < EDD * DD; idx += 512) {
        int j = idx >> 7, c = idx & 127;
        WeT[c * 65 + j] = We[idx];
    }
    __syncthreads();

    int wave = tid >> 6, lane = tid & 63;
    int n = blockIdx.x * 8 + wave;
    if (n >= N) return;

    int jj = lane & 7;
    int gbase = lane & 56;           // 8*g
    int c0 = lane * 2;

    float2 qv  = *(const float2*)&q[(size_t)n * DD + c0];
    float2 bev = *(const float2*)&be[c0];

    // qbe (group-uniform per head)
    float t = qv.x * bev.x + qv.y * bev.y;
    t += __shfl_xor(t, 1); t += __shfl_xor(t, 2); t += __shfl_xor(t, 4);
    float qbe = t;

    // qWe[r] = sum_c q[n,16g+c] * We[jj+8r][16g+c]
    float qWe[8];
    #pragma unroll
    for (int r = 0; r < 8; r++) qWe[r] = 0.f;
    #pragma unroll
    for (int cc = 0; cc < 8; cc++) {
        float q0 = __shfl(qv.x, gbase + cc);
        float q1 = __shfl(qv.y, gbase + cc);
        const float* w0 = &WeT[((gbase << 1) + 2 * cc) * 65 + jj];
        const float* w1 = w0 + 65;
        #pragma unroll
        for (int r = 0; r < 8; r++)
            qWe[r] += q0 * w0[8 * r] + q1 * w1[8 * r];
    }

    int start = indptr[n], end = indptr[n + 1];
    float m = -INFINITY, s = 0.f, av0 = 0.f, av1 = 0.f;
    float aea[8];
    #pragma unroll
    for (int r = 0; r < 8; r++) aea[r] = 0.f;

    for (int ii = start; ii < end; ii++) {
        int src = ssrc[ii];
        int eid = seid[ii];
        float ea = edge_attr[(size_t)eid * EDD + lane];
        float2 kv = *(const float2*)&k[(size_t)src * DD + c0];
        float2 vv = *(const float2*)&v[(size_t)src * DD + c0];
        float ear[8];
        #pragma unroll
        for (int r = 0; r < 8; r++) ear[r] = __shfl(ea, jj + 8 * r);
        float part = qv.x * kv.x + qv.y * kv.y;
        #pragma unroll
        for (int r = 0; r < 8; r++) part += ear[r] * qWe[r];
        part += __shfl_xor(part, 1);
        part += __shfl_xor(part, 2);
        part += __shfl_xor(part, 4);
        float alpha = (part + qbe) * 0.25f;
        float nm = fmaxf(m, alpha);
        float sc = __expf(m - nm);    // first edge: exp(-inf)=0
        float p  = __expf(alpha - nm);
        s = s * sc + p;
        av0 = av0 * sc + p * vv.x;
        av1 = av1 * sc + p * vv.y;
        #pragma unroll
        for (int r = 0; r < 8; r++) aea[r] = aea[r] * sc + p * ear[r];
        m = nm;
    }

    if (end > start) {
        float inv = 1.f / s;
        // out_e[c0] = sum_j aea[g][j] * We[j][c0]  (coalesced global We row reads)
        float oe0 = 0.f, oe1 = 0.f;
        #pragma unroll
        for (int r = 0; r < 8; r++) {
            #pragma unroll
            for (int j2 = 0; j2 < 8; j2++) {
                float a = __shfl(aea[r], gbase + j2);
                float2 w = *(const float2*)&We[(size_t)(j2 + 8 * r) * DD + c0];
                oe0 += a * w.x; oe1 += a * w.y;
            }
        }
        size_t o = (size_t)n * DD + c0;
        pre[o]     += (av0 + oe0) * inv + bev.x;
        pre[o + 1] += (av1 + oe1) * inv + bev.y;
    }
}

// ---------------- pack a [128][128] fp32 weight into bf16 MFMA B-fragment order ----------------
__global__ __launch_bounds__(256) void packw_kernel(const float* __restrict__ w,
                                                    unsigned short* __restrict__ packed)
{
    int idx = blockIdx.x * 256 + threadIdx.x;
    if (idx >= DD * DD) return;
    int j    = idx & 7;
    int lane = (idx >> 3) & 63;
    int kt   = (idx >> 9) & 3;
    int ncf  = idx >> 11;
    int kk  = kt * 32 + (lane >> 4) * 8 + j;
    int col = ncf * 16 + (lane & 15);
    packed[idx] = f2bf(w[kk * DD + col]);
}

// ---------------- subgraph branch via MFMA ----------------
__global__ __launch_bounds__(256, 4) void submlp_mfma_kernel(
    const float* __restrict__ x, const int* __restrict__ sub_nodes, const int* __restrict__ sub_ind,
    const float* __restrict__ sn_g, const float* __restrict__ sn_b,
    const unsigned short* __restrict__ packB1, const float* __restrict__ p1b,
    const unsigned short* __restrict__ packB2, const float* __restrict__ p2b,
    float* __restrict__ accum, int M)
{
    __shared__ unsigned short sxs[64 * DD];
    __shared__ unsigned short hss[64 * DD];
    __shared__ int segS[64];
    int tid = threadIdx.x;
    int lane = tid & 63, wid = tid >> 6;
    size_t m0 = (size_t)blockIdx.x * 64;

    if (tid < 64) {
        size_t row = m0 + tid;
        segS[tid] = (row < (size_t)M) ? sub_ind[row] : -1;
    }

    {
        float g0 = sn_g[2 * lane], g1 = sn_g[2 * lane + 1];
        float b0 = sn_b[2 * lane], b1 = sn_b[2 * lane + 1];
        #pragma unroll
        for (int r = 0; r < 16; r++) {
            int tr = wid * 16 + r;
            size_t row = m0 + tr;
            float v0 = 0.f, v1 = 0.f;
            if (row < (size_t)M) {
                int node = sub_nodes[row];
                float2 xv = *(const float2*)&x[(size_t)node * DD + 2 * lane];
                v0 = xv.x; v1 = xv.y;
            }
            float s1 = v0 + v1, s2 = v0 * v0 + v1 * v1;
            #pragma unroll
            for (int o = 32; o >= 1; o >>= 1) { s1 += __shfl_xor(s1, o); s2 += __shfl_xor(s2, o); }
            float mean = s1 * (1.f / DD);
            float var  = s2 * (1.f / DD) - mean * mean;
            float rs = rsqrtf(var + 1e-5f);
            float n0 = (v0 - mean) * rs * g0 + b0;
            float n1 = (v1 - mean) * rs * g1 + b1;
            unsigned int uidx = ((unsigned)(tr * 64 + lane)) ^ (((unsigned)tr & 7u) << 2);
            ((unsigned int*)sxs)[uidx] = pack2bf16(n0, n1);
        }
    }
    __syncthreads();

    int wr = wid >> 1, wc = wid & 1;
    int rA = wr * 32 + (lane & 15);
    int kb = (lane >> 4) * 8;

    f32x4 acc[2][4];
    #pragma unroll
    for (int i = 0; i < 2; i++)
        #pragma unroll
        for (int j = 0; j < 4; j++) acc[i][j] = (f32x4){0.f, 0.f, 0.f, 0.f};

    #pragma unroll
    for (int kt = 0; kt < 4; kt++) {
        int k0 = kt * 32 + kb;
        bf16x8 a0 = *(const bf16x8*)&sxs[((rA)      * DD + k0) ^ ((rA & 7) << 3)];
        int rA1 = rA + 16;
        bf16x8 a1 = *(const bf16x8*)&sxs[((rA1)     * DD + k0) ^ ((rA1 & 7) << 3)];
        #pragma unroll
        for (int nc = 0; nc < 4; nc++) {
            bf16x8 b = *(const bf16x8*)&packB1[(((wc * 4 + nc) * 4 + kt) * 64 + lane) * 8];
            acc[0][nc] = __builtin_amdgcn_mfma_f32_16x16x32_bf16(a0, b, acc[0][nc], 0, 0, 0);
            acc[1][nc] = __builtin_amdgcn_mfma_f32_16x16x32_bf16(a1, b, acc[1][nc], 0, 0, 0);
        }
    }

    {
        float bias1[4];
        #pragma unroll
        for (int nc = 0; nc < 4; nc++) bias1[nc] = p1b[wc * 64 + nc * 16 + (lane & 15)];
        #pragma unroll
        for (int mrf = 0; mrf < 2; mrf++) {
            int rbase = wr * 32 + mrf * 16 + (lane >> 4) * 4;
            #pragma unroll
            for (int nc = 0; nc < 4; nc++) {
                int col = wc * 64 + nc * 16 + (lane & 15);
                #pragma unroll
                for (int j = 0; j < 4; j++) {
                    float h = acc[mrf][nc][j] + bias1[nc];
                    h = h / (1.f + expf(-h));
                    int rr = rbase + j;
                    hss[(rr * DD + col) ^ ((rr & 7) << 3)] = f2bf(h);
                }
            }
        }
    }
    __syncthreads();

    f32x4 acc2[2][4];
    #pragma unroll
    for (int i = 0; i < 2; i++)
        #pragma unroll
        for (int j = 0; j < 4; j++) acc2[i][j] = (f32x4){0.f, 0.f, 0.f, 0.f};

    #pragma unroll
    for (int kt = 0; kt < 4; kt++) {
        int k0 = kt * 32 + kb;
        bf16x8 a0 = *(const bf16x8*)&hss[((rA)      * DD + k0) ^ ((rA & 7) << 3)];
        int rA1 = rA + 16;
        bf16x8 a1 = *(const bf16x8*)&hss[((rA1)     * DD + k0) ^ ((rA1 & 7) << 3)];
        #pragma unroll
        for (int nc = 0; nc < 4; nc++) {
            bf16x8 b = *(const bf16x8*)&packB2[(((wc * 4 + nc) * 4 + kt) * 64 + lane) * 8];
            acc2[0][nc] = __builtin_amdgcn_mfma_f32_16x16x32_bf16(a0, b, acc2[0][nc], 0, 0, 0);
            acc2[1][nc] = __builtin_amdgcn_mfma_f32_16x16x32_bf16(a1, b, acc2[1][nc], 0, 0, 0);
        }
    }

    {
        float bias2[4];
        #pragma unroll
        for (int nc = 0; nc < 4; nc++) bias2[nc] = p2b[wc * 64 + nc * 16 + (lane & 15)];
        #pragma unroll
        for (int mrf = 0; mrf < 2; mrf++) {
            int rbase = wr * 32 + mrf * 16 + (lane >> 4) * 4;
            #pragma unroll
            for (int j = 0; j < 4; j++) {
                int rr = rbase + j;
                int seg = segS[rr];
                if (seg >= 0) {
                    #pragma unroll
                    for (int nc = 0; nc < 4; nc++) {
                        int col = wc * 64 + nc * 16 + (lane & 15);
                        atomicAdd(&accum[(size_t)seg * DD + col], acc2[mrf][nc][j] + bias2[nc]);
                    }
                }
            }
        }
    }
}

// ---------------- final combine: LN + SiLU ----------------
__global__ __launch_bounds__(128) void final_kernel(
    const float* __restrict__ pre, const float* __restrict__ accum, const int* __restrict__ cnt,
    const float* __restrict__ on_g, const float* __restrict__ on_b,
    float* __restrict__ out, int N)
{
    __shared__ float red[4];
    int tid = threadIdx.x;
    int n = blockIdx.x;
    float inv = 1.f / fmaxf((float)cnt[n], 1.f);
    size_t o = (size_t)n * DD + tid;
    float val = pre[o] + accum[o] * inv;
    float s1 = val, s2 = val * val;
    for (int off = 32; off >= 1; off >>= 1) { s1 += __shfl_xor(s1, off); s2 += __shfl_xor(s2, off); }
    int w = tid >> 6;
    if ((tid & 63) == 0) { red[2 * w] = s1; red[2 * w + 1] = s2; }
    __syncthreads();
    float mean = (red[0] + red[2]) * (1.f / DD);
    float var  = (red[1] + red[3]) * (1.f / DD) - mean * mean;
    float ov = (val - mean) * rsqrtf(var + 1e-5f) * on_g[tid] + on_b[tid];
    out[o] = ov / (1.f + expf(-ov));
}

extern "C" void kernel_launch(void* const* d_in, const int* in_sizes, int n_in,
                              void* d_out, int out_size, void* d_ws, size_t ws_size,
                              hipStream_t stream)
{
    const float* x         = (const float*)d_in[0];
    const int*   edge_index= (const int*)  d_in[1];
    const float* edge_attr = (const float*)d_in[2];
    const int*   sub_nodes = (const int*)  d_in[3];
    const int*   sub_ind   = (const int*)  d_in[4];
    const float* Wq = (const float*)d_in[5];  const float* bq = (const float*)d_in[6];
    const float* Wk = (const float*)d_in[7];  const float* bk = (const float*)d_in[8];
    const float* Wv = (const float*)d_in[9];  const float* bv = (const float*)d_in[10];
    const float* We = (const float*)d_in[11]; const float* be = (const float*)d_in[12];
    const float* Ws = (const float*)d_in[13]; const float* bs = (const float*)d_in[14];
    const float* sn_g = (const float*)d_in[15]; const float* sn_b = (const float*)d_in[16];
    const float* p1w = (const float*)d_in[17]; const float* p1b = (const float*)d_in[18];
    const float* p2w = (const float*)d_in[19]; const float* p2b = (const float*)d_in[20];
    const float* on_g = (const float*)d_in[21]; const float* on_b = (const float*)d_in[22];

    int N = in_sizes[0] / DD;
    int E = in_sizes[1] / 2;
    int M = in_sizes[3];
    float* out = (float*)d_out;

    unsigned short* packB1 = (unsigned short*)d_ws;
    unsigned short* packB2 = packB1 + DD * DD;
    size_t ND = (size_t)N * DD;
    float* q     = (float*)(packB2 + DD * DD);
    float* k     = q + ND;
    float* v     = k + ND;
    float* pre   = v + ND;
    float* accum = pre + ND;
    int* indptr = (int*)(accum + ND);
    int* fill   = indptr + (N + 1);
    int* deg    = fill + N;
    int* cnt    = deg + N;
    int* ssrc   = cnt + N;
    int* seid   = ssrc + E;

    const int* srcA = edge_index;
    const int* dstA = edge_index + E;

    hipMemsetAsync(deg, 0, (size_t)N * sizeof(int), stream);
    hipMemsetAsync(cnt, 0, (size_t)N * sizeof(int), stream);
    hipMemsetAsync(accum, 0, ND * sizeof(float), stream);

    packw_kernel<<<(DD * DD + 255) / 256, 256, 0, stream>>>(p1w, packB1);
    packw_kernel<<<(DD * DD + 255) / 256, 256, 0, stream>>>(p2w, packB2);

    lin4_kernel<<<(N + 3) / 4, 128, 0, stream>>>(x, Wq, bq, Wk, bk, Wv, bv, Ws, bs, q, k, v, pre, N);
    count_kernel<<<2048, 256, 0, stream>>>(dstA, E, deg);
    count_kernel<<<2048, 256, 0, stream>>>(sub_ind, M, cnt);
    scan_kernel<<<1, 1024, 0, stream>>>(deg, N, indptr, fill);
    escatter_kernel<<<2048, 256, 0, stream>>>(srcA, dstA, E, fill, ssrc, seid);
    attn_kernel<<<(N + 7) / 8, 512, 0, stream>>>(q, k, v, edge_attr, We, be, indptr, ssrc, seid, pre, N);
    submlp_mfma_kernel<<<(M + 63) / 64, 256, 0, stream>>>(x, sub_nodes, sub_ind, sn_g, sn_b,
                                                          packB1, p1b, packB2, p2b, accum, M);
    final_kernel<<<N, 128, 0, stream>>>(pre, accum, cnt, on_g, on_b, out, N);
}

// Round 4
// 1201.878 us; speedup vs baseline: 2.4923x; 1.0561x over previous
//
#include <hip/hip_runtime.h>
#include <math.h>

#define DD 128
#define EDD 64

typedef __attribute__((ext_vector_type(8))) short bf16x8;
typedef __attribute__((ext_vector_type(4))) float f32x4;

__device__ inline unsigned short f2bf(float f) {
    unsigned int u = __float_as_uint(f);
    u += 0x7FFFu + ((u >> 16) & 1u);
    return (unsigned short)(u >> 16);
}
__device__ inline unsigned int pack2bf16(float lo, float hi) {
    return (unsigned int)f2bf(lo) | ((unsigned int)f2bf(hi) << 16);
}

// ---------------- fused q/k/v/skip linears: 4 rows per 128-thread block ----------------
__global__ __launch_bounds__(128) void lin4_kernel(
    const float* __restrict__ x,
    const float* __restrict__ Wq, const float* __restrict__ bq,
    const float* __restrict__ Wk, const float* __restrict__ bk,
    const float* __restrict__ Wv, const float* __restrict__ bv,
    const float* __restrict__ Ws, const float* __restrict__ bs,
    float* __restrict__ q, float* __restrict__ k, float* __restrict__ v,
    float* __restrict__ pre, int N)
{
    __shared__ float xs[4][DD];
    int tid = threadIdx.x;
    int r0 = blockIdx.x * 4;
    for (int r = 0; r < 4; r++) {
        int row = r0 + r;
        xs[r][tid] = (row < N) ? x[(size_t)row * DD + tid] : 0.f;
    }
    __syncthreads();
    float aq[4], ak[4], av[4], as_[4];
    float bqv = bq[tid], bkv = bk[tid], bvv = bv[tid], bsv = bs[tid];
    #pragma unroll
    for (int r = 0; r < 4; r++) { aq[r] = bqv; ak[r] = bkv; av[r] = bvv; as_[r] = bsv; }
    for (int kk = 0; kk < DD; kk++) {
        float wq = Wq[kk * DD + tid], wk = Wk[kk * DD + tid];
        float wv = Wv[kk * DD + tid], ws = Ws[kk * DD + tid];
        #pragma unroll
        for (int r = 0; r < 4; r++) {
            float xv = xs[r][kk];
            aq[r] += xv * wq; ak[r] += xv * wk; av[r] += xv * wv; as_[r] += xv * ws;
        }
    }
    for (int r = 0; r < 4; r++) {
        int row = r0 + r;
        if (row >= N) break;
        size_t o = (size_t)row * DD + tid;
        q[o] = aq[r]; k[o] = ak[r]; v[o] = av[r];
        pre[o] = xs[r][tid] + as_[r];   // x + (x@Ws + bs)
    }
}

// ---------------- histogram ----------------
__global__ void count_kernel(const int* __restrict__ idx, int n, int* __restrict__ cnt)
{
    int i = blockIdx.x * blockDim.x + threadIdx.x;
    int stride = gridDim.x * blockDim.x;
    for (; i < n; i += stride) atomicAdd(&cnt[idx[i]], 1);
}

// ---------------- single-block exclusive scan ----------------
__global__ __launch_bounds__(1024) void scan_kernel(const int* __restrict__ deg, int N,
                                                    int* __restrict__ indptr, int* __restrict__ fill)
{
    __shared__ int s[1024];
    int tid = threadIdx.x;
    int running = 0;
    for (int base = 0; base < N; base += 1024) {
        int i = base + tid;
        int val = (i < N) ? deg[i] : 0;
        s[tid] = val; __syncthreads();
        for (int off = 1; off < 1024; off <<= 1) {
            int t = (tid >= off) ? s[tid - off] : 0;
            __syncthreads();
            s[tid] += t;
            __syncthreads();
        }
        int excl = s[tid] - val;
        if (i < N) { indptr[i] = running + excl; fill[i] = running + excl; }
        int tot = s[1023];
        __syncthreads();
        running += tot;
    }
    if (tid == 0) indptr[N] = running;
}

// ---------------- scatter edge ids into dst-CSR ----------------
__global__ void escatter_kernel(const int* __restrict__ srcA, const int* __restrict__ dstA, int E,
                                int* __restrict__ fill, int* __restrict__ ssrc, int* __restrict__ seid)
{
    int i = blockIdx.x * blockDim.x + threadIdx.x;
    int stride = gridDim.x * blockDim.x;
    for (; i < E; i += stride) {
        int d = dstA[i];
        int pos = atomicAdd(&fill[d], 1);
        ssrc[pos] = srcA[i];
        seid[pos] = i;
    }
}

// ---------------- scatter subgraph rows into segment-sorted order ----------------
__global__ void sscatter_kernel(const int* __restrict__ sub_nodes, const int* __restrict__ sub_ind,
                                int M, int* __restrict__ sfill,
                                int* __restrict__ snode, int* __restrict__ sseg)
{
    int i = blockIdx.x * blockDim.x + threadIdx.x;
    int stride = gridDim.x * blockDim.x;
    for (; i < M; i += stride) {
        int seg = sub_ind[i];
        int pos = atomicAdd(&sfill[seg], 1);
        snode[pos] = sub_nodes[i];
        sseg[pos] = seg;
    }
}

// ---------------- attention: 1 wave per dst node, algebraic e-refactor ----------------
__global__ __launch_bounds__(512, 6) void attn_kernel(
    const float* __restrict__ q, const float* __restrict__ k, const float* __restrict__ v,
    const float* __restrict__ edge_attr, const float* __restrict__ We, const float* __restrict__ be,
    const int* __restrict__ indptr, const int* __restrict__ ssrc, const int* __restrict__ seid,
    float* __restrict__ pre, int N)
{
    __shared__ float WeT[DD * 65];
    int tid = threadIdx.x;
    for (int idx = tid; idx < EDD * DD; idx += 512) {
        int j = idx >> 7, c = idx & 127;
        WeT[c * 65 + j] = We[idx];
    }
    __syncthreads();

    int wave = tid >> 6, lane = tid & 63;
    int n = blockIdx.x * 8 + wave;
    if (n >= N) return;

    int jj = lane & 7;
    int gbase = lane & 56;
    int c0 = lane * 2;

    float2 qv  = *(const float2*)&q[(size_t)n * DD + c0];
    float2 bev = *(const float2*)&be[c0];

    float t = qv.x * bev.x + qv.y * bev.y;
    t += __shfl_xor(t, 1); t += __shfl_xor(t, 2); t += __shfl_xor(t, 4);
    float qbe = t;

    float qWe[8];
    #pragma unroll
    for (int r = 0; r < 8; r++) qWe[r] = 0.f;
    #pragma unroll
    for (int cc = 0; cc < 8; cc++) {
        float q0 = __shfl(qv.x, gbase + cc);
        float q1 = __shfl(qv.y, gbase + cc);
        const float* w0 = &WeT[((gbase << 1) + 2 * cc) * 65 + jj];
        const float* w1 = w0 + 65;
        #pragma unroll
        for (int r = 0; r < 8; r++)
            qWe[r] += q0 * w0[8 * r] + q1 * w1[8 * r];
    }

    int start = indptr[n], end = indptr[n + 1];
    float m = -INFINITY, s = 0.f, av0 = 0.f, av1 = 0.f;
    float aea[8];
    #pragma unroll
    for (int r = 0; r < 8; r++) aea[r] = 0.f;

    for (int ii = start; ii < end; ii++) {
        int src = ssrc[ii];
        int eid = seid[ii];
        float ea = edge_attr[(size_t)eid * EDD + lane];
        float2 kv = *(const float2*)&k[(size_t)src * DD + c0];
        float2 vv = *(const float2*)&v[(size_t)src * DD + c0];
        float ear[8];
        #pragma unroll
        for (int r = 0; r < 8; r++) ear[r] = __shfl(ea, jj + 8 * r);
        float part = qv.x * kv.x + qv.y * kv.y;
        #pragma unroll
        for (int r = 0; r < 8; r++) part += ear[r] * qWe[r];
        part += __shfl_xor(part, 1);
        part += __shfl_xor(part, 2);
        part += __shfl_xor(part, 4);
        float alpha = (part + qbe) * 0.25f;
        float nm = fmaxf(m, alpha);
        float sc = __expf(m - nm);
        float p  = __expf(alpha - nm);
        s = s * sc + p;
        av0 = av0 * sc + p * vv.x;
        av1 = av1 * sc + p * vv.y;
        #pragma unroll
        for (int r = 0; r < 8; r++) aea[r] = aea[r] * sc + p * ear[r];
        m = nm;
    }

    if (end > start) {
        float inv = 1.f / s;
        float oe0 = 0.f, oe1 = 0.f;
        #pragma unroll
        for (int r = 0; r < 8; r++) {
            #pragma unroll
            for (int j2 = 0; j2 < 8; j2++) {
                float a = __shfl(aea[r], gbase + j2);
                float2 w = *(const float2*)&We[(size_t)(j2 + 8 * r) * DD + c0];
                oe0 += a * w.x; oe1 += a * w.y;
            }
        }
        size_t o = (size_t)n * DD + c0;
        pre[o]     += (av0 + oe0) * inv + bev.x;
        pre[o + 1] += (av1 + oe1) * inv + bev.y;
    }
}

// ---------------- pack a [128][128] fp32 weight into bf16 MFMA B-fragment order ----------------
__global__ __launch_bounds__(256) void packw_kernel(const float* __restrict__ w,
                                                    unsigned short* __restrict__ packed)
{
    int idx = blockIdx.x * 256 + threadIdx.x;
    if (idx >= DD * DD) return;
    int j    = idx & 7;
    int lane = (idx >> 3) & 63;
    int kt   = (idx >> 9) & 3;
    int ncf  = idx >> 11;
    int kk  = kt * 32 + (lane >> 4) * 8 + j;
    int col = ncf * 16 + (lane & 15);
    packed[idx] = f2bf(w[kk * DD + col]);
}

// ---------------- subgraph branch v3: segment-sorted, in-place LDS, run-length reduced atomics
// 64 sorted rows/block, 256 threads (2x2 waves). LDS: one 16 KB buffer (sxs -> hss -> fp32 out half)
__global__ __launch_bounds__(256, 8) void submlp_mfma_kernel(
    const float* __restrict__ x, const int* __restrict__ snode, const int* __restrict__ sseg,
    const float* __restrict__ sn_g, const float* __restrict__ sn_b,
    const unsigned short* __restrict__ packB1, const float* __restrict__ p1b,
    const unsigned short* __restrict__ packB2, const float* __restrict__ p2b,
    float* __restrict__ accum, int M)
{
    __shared__ unsigned short sxs[64 * DD];   // 16 KB; reused in-place for hs, then fp32 out half-tile
    __shared__ int segS[64];
    float* outS = (float*)sxs;                // [32][128] fp32 view

    int tid = threadIdx.x;
    int lane = tid & 63, wid = tid >> 6;
    size_t m0 = (size_t)blockIdx.x * 64;

    if (tid < 64) {
        size_t row = m0 + tid;
        segS[tid] = (row < (size_t)M) ? sseg[row] : -1;
    }

    // ---- LN phase: wave wid owns tile rows [wid*16, wid*16+16) ----
    {
        int nid = 0;
        {
            size_t row = m0 + wid * 16 + (lane & 15);
            if (lane < 16 && row < (size_t)M) nid = snode[row];
        }
        float g0 = sn_g[2 * lane], g1 = sn_g[2 * lane + 1];
        float b0 = sn_b[2 * lane], b1 = sn_b[2 * lane + 1];
        #pragma unroll
        for (int r = 0; r < 16; r++) {
            int tr = wid * 16 + r;
            size_t row = m0 + tr;
            int node = __shfl(nid, r);
            float v0 = 0.f, v1 = 0.f;
            if (row < (size_t)M) {
                float2 xv = *(const float2*)&x[(size_t)node * DD + 2 * lane];
                v0 = xv.x; v1 = xv.y;
            }
            float s1 = v0 + v1, s2 = v0 * v0 + v1 * v1;
            #pragma unroll
            for (int o = 32; o >= 1; o >>= 1) { s1 += __shfl_xor(s1, o); s2 += __shfl_xor(s2, o); }
            float mean = s1 * (1.f / DD);
            float var  = s2 * (1.f / DD) - mean * mean;
            float rs = rsqrtf(var + 1e-5f);
            float n0 = (v0 - mean) * rs * g0 + b0;
            float n1 = (v1 - mean) * rs * g1 + b1;
            unsigned int uidx = ((unsigned)(tr * 64 + lane)) ^ (((unsigned)tr & 7u) << 2);
            ((unsigned int*)sxs)[uidx] = pack2bf16(n0, n1);
        }
    }
    __syncthreads();

    int wr = wid >> 1, wc = wid & 1;
    int rA = wr * 32 + (lane & 15);
    int kb = (lane >> 4) * 8;

    // ---- GEMM1 ----
    f32x4 acc[2][4];
    #pragma unroll
    for (int i = 0; i < 2; i++)
        #pragma unroll
        for (int j = 0; j < 4; j++) acc[i][j] = (f32x4){0.f, 0.f, 0.f, 0.f};

    #pragma unroll
    for (int kt = 0; kt < 4; kt++) {
        int k0 = kt * 32 + kb;
        bf16x8 a0 = *(const bf16x8*)&sxs[((rA)      * DD + k0) ^ ((rA & 7) << 3)];
        int rA1 = rA + 16;
        bf16x8 a1 = *(const bf16x8*)&sxs[((rA1)     * DD + k0) ^ ((rA1 & 7) << 3)];
        #pragma unroll
        for (int nc = 0; nc < 4; nc++) {
            bf16x8 b = *(const bf16x8*)&packB1[(((wc * 4 + nc) * 4 + kt) * 64 + lane) * 8];
            acc[0][nc] = __builtin_amdgcn_mfma_f32_16x16x32_bf16(a0, b, acc[0][nc], 0, 0, 0);
            acc[1][nc] = __builtin_amdgcn_mfma_f32_16x16x32_bf16(a1, b, acc[1][nc], 0, 0, 0);
        }
    }
    __syncthreads();   // all GEMM1 A-reads done before in-place overwrite

    // epilogue1: bias + SiLU -> bf16 -> back into sxs (in place, same swizzle)
    {
        float bias1[4];
        #pragma unroll
        for (int nc = 0; nc < 4; nc++) bias1[nc] = p1b[wc * 64 + nc * 16 + (lane & 15)];
        #pragma unroll
        for (int mrf = 0; mrf < 2; mrf++) {
            int rbase = wr * 32 + mrf * 16 + (lane >> 4) * 4;
            #pragma unroll
            for (int nc = 0; nc < 4; nc++) {
                int col = wc * 64 + nc * 16 + (lane & 15);
                #pragma unroll
                for (int j = 0; j < 4; j++) {
                    float h = acc[mrf][nc][j] + bias1[nc];
                    h = h / (1.f + __expf(-h));
                    int rr = rbase + j;
                    sxs[(rr * DD + col) ^ ((rr & 7) << 3)] = f2bf(h);
                }
            }
        }
    }
    __syncthreads();

    // ---- GEMM2 ----
    f32x4 acc2[2][4];
    #pragma unroll
    for (int i = 0; i < 2; i++)
        #pragma unroll
        for (int j = 0; j < 4; j++) acc2[i][j] = (f32x4){0.f, 0.f, 0.f, 0.f};

    #pragma unroll
    for (int kt = 0; kt < 4; kt++) {
        int k0 = kt * 32 + kb;
        bf16x8 a0 = *(const bf16x8*)&sxs[((rA)      * DD + k0) ^ ((rA & 7) << 3)];
        int rA1 = rA + 16;
        bf16x8 a1 = *(const bf16x8*)&sxs[((rA1)     * DD + k0) ^ ((rA1 & 7) << 3)];
        #pragma unroll
        for (int nc = 0; nc < 4; nc++) {
            bf16x8 b = *(const bf16x8*)&packB2[(((wc * 4 + nc) * 4 + kt) * 64 + lane) * 8];
            acc2[0][nc] = __builtin_amdgcn_mfma_f32_16x16x32_bf16(a0, b, acc2[0][nc], 0, 0, 0);
            acc2[1][nc] = __builtin_amdgcn_mfma_f32_16x16x32_bf16(a1, b, acc2[1][nc], 0, 0, 0);
        }
    }
    __syncthreads();   // all GEMM2 A-reads done before outS overwrite

    // ---- epilogue2: two 32-row halves -> fp32 LDS -> run-length reduce -> atomics ----
    float bias2[4];
    #pragma unroll
    for (int nc = 0; nc < 4; nc++) bias2[nc] = p2b[wc * 64 + nc * 16 + (lane & 15)];

    #pragma unroll
    for (int half = 0; half < 2; half++) {
        if (wr == half) {
            #pragma unroll
            for (int mrf = 0; mrf < 2; mrf++) {
                int rloc = mrf * 16 + (lane >> 4) * 4;
                #pragma unroll
                for (int nc = 0; nc < 4; nc++) {
                    int col = wc * 64 + nc * 16 + (lane & 15);
                    #pragma unroll
                    for (int j = 0; j < 4; j++)
                        outS[(rloc + j) * DD + col] = acc2[mrf][nc][j] + bias2[nc];
                }
            }
        }
        __syncthreads();
        // run-length reduce: thread -> (col, 16-row strip)
        {
            int col = tid & 127;
            int r0 = (tid >> 7) * 16;
            float racc = 0.f;
            int cseg = -1;
            for (int r = r0; r < r0 + 16; r++) {
                int seg = segS[half * 32 + r];
                if (seg != cseg) {
                    if (cseg >= 0) atomicAdd(&accum[(size_t)cseg * DD + col], racc);
                    racc = 0.f; cseg = seg;
                }
                if (seg >= 0) racc += outS[r * DD + col];
            }
            if (cseg >= 0) atomicAdd(&accum[(size_t)cseg * DD + col], racc);
        }
        __syncthreads();
    }
}

// ---------------- final combine: LN + SiLU ----------------
__global__ __launch_bounds__(128) void final_kernel(
    const float* __restrict__ pre, const float* __restrict__ accum, const int* __restrict__ cnt,
    const float* __restrict__ on_g, const float* __restrict__ on_b,
    float* __restrict__ out, int N)
{
    __shared__ float red[4];
    int tid = threadIdx.x;
    int n = blockIdx.x;
    float inv = 1.f / fmaxf((float)cnt[n], 1.f);
    size_t o = (size_t)n * DD + tid;
    float val = pre[o] + accum[o] * inv;
    float s1 = val, s2 = val * val;
    for (int off = 32; off >= 1; off >>= 1) { s1 += __shfl_xor(s1, off); s2 += __shfl_xor(s2, off); }
    int w = tid >> 6;
    if ((tid & 63) == 0) { red[2 * w] = s1; red[2 * w + 1] = s2; }
    __syncthreads();
    float mean = (red[0] + red[2]) * (1.f / DD);
    float var  = (red[1] + red[3]) * (1.f / DD) - mean * mean;
    float ov = (val - mean) * rsqrtf(var + 1e-5f) * on_g[tid] + on_b[tid];
    out[o] = ov / (1.f + __expf(-ov));
}

extern "C" void kernel_launch(void* const* d_in, const int* in_sizes, int n_in,
                              void* d_out, int out_size, void* d_ws, size_t ws_size,
                              hipStream_t stream)
{
    const float* x         = (const float*)d_in[0];
    const int*   edge_index= (const int*)  d_in[1];
    const float* edge_attr = (const float*)d_in[2];
    const int*   sub_nodes = (const int*)  d_in[3];
    const int*   sub_ind   = (const int*)  d_in[4];
    const float* Wq = (const float*)d_in[5];  const float* bq = (const float*)d_in[6];
    const float* Wk = (const float*)d_in[7];  const float* bk = (const float*)d_in[8];
    const float* Wv = (const float*)d_in[9];  const float* bv = (const float*)d_in[10];
    const float* We = (const float*)d_in[11]; const float* be = (const float*)d_in[12];
    const float* Ws = (const float*)d_in[13]; const float* bs = (const float*)d_in[14];
    const float* sn_g = (const float*)d_in[15]; const float* sn_b = (const float*)d_in[16];
    const float* p1w = (const float*)d_in[17]; const float* p1b = (const float*)d_in[18];
    const float* p2w = (const float*)d_in[19]; const float* p2b = (const float*)d_in[20];
    const float* on_g = (const float*)d_in[21]; const float* on_b = (const float*)d_in[22];

    int N = in_sizes[0] / DD;
    int E = in_sizes[1] / 2;
    int M = in_sizes[3];
    float* out = (float*)d_out;

    unsigned short* packB1 = (unsigned short*)d_ws;
    unsigned short* packB2 = packB1 + DD * DD;
    size_t ND = (size_t)N * DD;
    float* q     = (float*)(packB2 + DD * DD);
    float* k     = q + ND;
    float* v     = k + ND;
    float* pre   = v + ND;
    float* accum = pre + ND;
    int* indptr  = (int*)(accum + ND);   // N+1
    int* fill    = indptr + (N + 1);     // N
    int* deg     = fill + N;             // N
    int* cnt     = deg + N;              // N
    int* sindptr = cnt + N;              // N+1
    int* sfill   = sindptr + (N + 1);    // N
    int* ssrc    = sfill + N;            // E
    int* seid    = ssrc + E;             // E
    int* snode   = seid + E;             // M
    int* sseg    = snode + M;            // M

    const int* srcA = edge_index;
    const int* dstA = edge_index + E;

    hipMemsetAsync(deg, 0, (size_t)N * sizeof(int), stream);
    hipMemsetAsync(cnt, 0, (size_t)N * sizeof(int), stream);
    hipMemsetAsync(accum, 0, ND * sizeof(float), stream);

    packw_kernel<<<(DD * DD + 255) / 256, 256, 0, stream>>>(p1w, packB1);
    packw_kernel<<<(DD * DD + 255) / 256, 256, 0, stream>>>(p2w, packB2);

    lin4_kernel<<<(N + 3) / 4, 128, 0, stream>>>(x, Wq, bq, Wk, bk, Wv, bv, Ws, bs, q, k, v, pre, N);
    count_kernel<<<2048, 256, 0, stream>>>(dstA, E, deg);
    count_kernel<<<2048, 256, 0, stream>>>(sub_ind, M, cnt);
    scan_kernel<<<1, 1024, 0, stream>>>(deg, N, indptr, fill);
    escatter_kernel<<<2048, 256, 0, stream>>>(srcA, dstA, E, fill, ssrc, seid);
    scan_kernel<<<1, 1024, 0, stream>>>(cnt, N, sindptr, sfill);
    sscatter_kernel<<<2048, 256, 0, stream>>>(sub_nodes, sub_ind, M, sfill, snode, sseg);
    attn_kernel<<<(N + 7) / 8, 512, 0, stream>>>(q, k, v, edge_attr, We, be, indptr, ssrc, seid, pre, N);
    submlp_mfma_kernel<<<(M + 63) / 64, 256, 0, stream>>>(x, snode, sseg, sn_g, sn_b,
                                                          packB1, p1b, packB2, p2b, accum, M);
    final_kernel<<<N, 128, 0, stream>>>(pre, accum, cnt, on_g, on_b, out, N);
}